// Round 3
// baseline (72.616 us; speedup 1.0000x reference)
//
#include <hip/hip_runtime.h>
#include <math.h>

#define B 64
#define N 16384
#define K 16
#define NCHUNK 16      // chunks per row
// ws layout (floats):
//   wsV  [B][NCHUNK][K]  candidate values   : 16384 floats @ 0
//   wsI  [B][NCHUNK][K]  candidate indices  : 16384 ints   @ 16384
//   wsS  [B][NCHUNK]     chunk exp sums     : 1024 floats  @ 32768
//   wsM  [B][NCHUNK]     chunk max          : 1024 floats  @ 33792
// total 34816 floats = 136 KB

typedef float f4 __attribute__((ext_vector_type(4)));

__device__ __forceinline__ void wave_argmax(float& vmax, int& imax) {
#pragma unroll
  for (int off = 32; off; off >>= 1) {
    const float ov = __shfl_down(vmax, off);
    const int   oi = __shfl_down(imax, off);
    if (ov > vmax || (ov == vmax && oi < imax)) { vmax = ov; imax = oi; }
  }
  vmax = __shfl(vmax, 0);
  imax = __shfl(imax, 0);
}

__device__ __forceinline__ float wave_sum(float v) {
#pragma unroll
  for (int off = 32; off; off >>= 1) v += __shfl_down(v, off);
  return v;
}

// ---------------- Kernel A: per-chunk top-16 candidates + exp partial sums ----------------
// 1024 blocks x 256 threads; block = (row b, chunk c) of 1024 contiguous elements.
__global__ __launch_bounds__(256)
void gtk_partial(const float* __restrict__ logits, const float* __restrict__ gumbel,
                 float* __restrict__ ws) {
  const int blk  = blockIdx.x;
  const int tid  = threadIdx.x;
  const int wave = tid >> 6, lane = tid & 63;
  const int b = blk >> 4, c = blk & 15;
  const size_t gbase = (size_t)blk << 10;

  const f4 lv = *(const f4*)(logits + gbase + (tid << 2));
  const f4 gv = *(const f4*)(gumbel + gbase + (tid << 2));
  float x[4];
#pragma unroll
  for (int e = 0; e < 4; ++e) x[e] = lv[e] + gv[e];
  const int myn = (c << 10) + (tid << 2);   // row-local index of x[0]

  __shared__ float sv[64];
  __shared__ int   si[64];
  __shared__ float spart[5];
  __shared__ float smc;

  // wave-local sequential top-16 over 256 elements (no barriers)
#pragma unroll 1
  for (int k = 0; k < K; ++k) {
    float vmax = -INFINITY; int imax = 0x7fffffff;
#pragma unroll
    for (int e = 0; e < 4; ++e)
      if (x[e] > vmax) { vmax = x[e]; imax = myn + e; }   // ascending e: first wins ties
    wave_argmax(vmax, imax);
    if (lane == 0) { sv[wave * K + k] = vmax; si[wave * K + k] = imax; }
#pragma unroll
    for (int e = 0; e < 4; ++e)
      if (myn + e == imax) x[e] = -INFINITY;
  }
  __syncthreads();

  // wave 0: merge 64 wave-candidates -> block top-16, write to ws
  if (wave == 0) {
    float cv = sv[lane]; int ci = si[lane];
    float mc = 0.f;
    float* wV = ws + ((size_t)b * NCHUNK + c) * K;
    int*   wI = (int*)(ws + 16384) + ((size_t)b * NCHUNK + c) * K;
#pragma unroll 1
    for (int k = 0; k < K; ++k) {
      float vmax = cv; int imax = ci;
      wave_argmax(vmax, imax);
      if (k == 0) { mc = vmax; if (lane == 0) smc = vmax; }
      if (lane == 0) { wV[k] = vmax; wI[k] = imax; }
      if (ci == imax) cv = -INFINITY;
    }
    // leftover: unselected wave-candidates, added back into the chunk sum
    float ls = wave_sum(__expf((cv - mc) * 1.5f));
    if (lane == 0) spart[4] = ls;
  }
  __syncthreads();

  const float mc = smc;
  float p = 0.f;
#pragma unroll
  for (int e = 0; e < 4; ++e) p += __expf((x[e] - mc) * 1.5f);  // masked -> exp(-inf)=0
  p = wave_sum(p);
  if (lane == 0) spart[wave] = p;
  __syncthreads();

  if (tid == 0) {
    const float S = spart[0] + spart[1] + spart[2] + spart[3] + spart[4];
    (ws + 32768)[b * NCHUNK + c] = S;
    (ws + 33792)[b * NCHUNK + c] = mc;
  }
}

// ---------------- Kernel B: row merge (wave 0) + plane writes (all waves) ----------------
// 1024 blocks x 256 threads; same element ownership as kernel A.
__global__ __launch_bounds__(256)
void gtk_write(const float* __restrict__ logits, const float* __restrict__ gumbel,
               const float* __restrict__ ws, float* __restrict__ st,
               float* __restrict__ softs) {
  const int blk  = blockIdx.x;
  const int tid  = threadIdx.x;
  const int wave = tid >> 6, lane = tid & 63;
  const int b = blk >> 4;
  const size_t gbase = (size_t)blk << 10;
  const int n0 = ((blk & 15) << 10) + (tid << 2);   // row-local index of my first elem

  __shared__ int   sei[K];
  __shared__ float sck[K];
  __shared__ float sm0;

  // issue input loads early; they fly while wave 0 merges
  const f4 lv = *(const f4*)(logits + gbase + (tid << 2));
  const f4 gv = *(const f4*)(gumbel + gbase + (tid << 2));

  if (wave == 0) {
    const float* wV = ws + (size_t)b * (NCHUNK * K);
    const int*   wI = (const int*)(ws + 16384) + (size_t)b * (NCHUNK * K);
    float cv[4]; int ci[4];
#pragma unroll
    for (int r = 0; r < 4; ++r) { cv[r] = wV[lane + 64 * r]; ci[r] = wI[lane + 64 * r]; }

    float m0 = 0.f;
    float ev[K];
#pragma unroll 1
    for (int k = 0; k < K; ++k) {
      float vmax = -INFINITY; int imax = 0x7fffffff;
#pragma unroll
      for (int r = 0; r < 4; ++r)
        if (cv[r] > vmax || (cv[r] == vmax && ci[r] < imax)) { vmax = cv[r]; imax = ci[r]; }
      wave_argmax(vmax, imax);
      if (k == 0) m0 = vmax;
      ev[k] = vmax;                      // note: only lane 0's copy is used below
      if (lane == 0) sei[k] = imax;
#pragma unroll
      for (int r = 0; r < 4; ++r)
        if (ci[r] == imax) cv[r] = -INFINITY;
    }

    // add back unselected candidates
    float ab = 0.f;
#pragma unroll
    for (int r = 0; r < 4; ++r) ab += __expf((cv[r] - m0) * 1.5f);
    ab = wave_sum(ab);

    if (lane == 0) {
      const float* wS = ws + 32768 + b * NCHUNK;
      const float* wM = ws + 33792 + b * NCHUNK;
      float A = ab;
#pragma unroll
      for (int c = 0; c < NCHUNK; ++c) A += wS[c] * __expf((wM[c] - m0) * 1.5f);
      float T = 0.f;
#pragma unroll
      for (int j = K - 1; j >= 0; --j) {
        T += __expf((ev[j] - m0) * 1.5f);
        sck[j] = 1.0f / (A + T);
      }
      sm0 = m0;
    }
  }
  __syncthreads();

  const float m0 = sm0;
  float E[4];
#pragma unroll
  for (int e = 0; e < 4; ++e) E[e] = __expf((lv[e] + gv[e] - m0) * 1.5f);

  int js[4] = {K, K, K, K};
#pragma unroll
  for (int j = 0; j < K; ++j) {
    const int idx = sei[j];
#pragma unroll
    for (int e = 0; e < 4; ++e)
      if (idx == n0 + e) js[e] = j;
  }

  const size_t plane = (size_t)B * N;
  const size_t o = gbase + (tid << 2);
#pragma unroll
  for (int k = 0; k < K; ++k) {
    const float ck = sck[k];
    f4 s, h;
#pragma unroll
    for (int e = 0; e < 4; ++e) {
      s[e] = (js[e] < k) ? 0.f : E[e] * ck;
      h[e] = (js[e] == k) ? 1.f : 0.f;
    }
    __builtin_nontemporal_store(s, (f4*)(softs + k * plane + o));
    __builtin_nontemporal_store(h, (f4*)(st    + k * plane + o));
  }
}

extern "C" void kernel_launch(void* const* d_in, const int* in_sizes, int n_in,
                              void* d_out, int out_size, void* d_ws, size_t ws_size,
                              hipStream_t stream) {
  const float* logits = (const float*)d_in[0];
  const float* gumbel = (const float*)d_in[1];
  float* st    = (float*)d_out;                      // [K,B,N]
  float* softs = st + (size_t)K * B * N;             // [K,B,N]
  float* ws    = (float*)d_ws;

  gtk_partial<<<B * NCHUNK, 256, 0, stream>>>(logits, gumbel, ws);
  gtk_write<<<B * NCHUNK, 256, 0, stream>>>(logits, gumbel, ws, st, softs);
}

// Round 4
// 70.792 us; speedup vs baseline: 1.0258x; 1.0258x over previous
//
#include <hip/hip_runtime.h>
#include <math.h>

#define B 64
#define N 16384
#define K 16
#define NCHUNK 16      // chunks per row (1024 elements each)
// ws layout (floats):
//   wsV  [B][NCHUNK][K]  candidate values   : 16384 floats @ 0
//   wsI  [B][NCHUNK][K]  candidate indices  : 16384 ints   @ 16384
//   wsS  [B][NCHUNK]     chunk exp sums     : 1024 floats  @ 32768
//   wsM  [B][NCHUNK]     chunk max          : 1024 floats  @ 33792
//   wsC  [B][48]         row constants      : 3072 floats  @ 34816
//        per row: c[0..15], idx[16..31] (int), m0 @ [32]

#define WSI_OFF 16384
#define WSS_OFF 32768
#define WSM_OFF 33792
#define WSC_OFF 34816

typedef float f4 __attribute__((ext_vector_type(4)));

__device__ __forceinline__ void wave_argmax(float& vmax, int& imax) {
#pragma unroll
  for (int off = 32; off; off >>= 1) {
    const float ov = __shfl_down(vmax, off);
    const int   oi = __shfl_down(imax, off);
    if (ov > vmax || (ov == vmax && oi < imax)) { vmax = ov; imax = oi; }
  }
  vmax = __shfl(vmax, 0);
  imax = __shfl(imax, 0);
}

__device__ __forceinline__ float wave_sum(float v) {
#pragma unroll
  for (int off = 32; off; off >>= 1) v += __shfl_down(v, off);
  return v;
}

// ---------------- Kernel A: per-chunk top-16 candidates + exp partial sums ----------------
// 1024 blocks x 256 threads; block = (row b, chunk c) of 1024 contiguous elements.
__global__ __launch_bounds__(256)
void gtk_partial(const float* __restrict__ logits, const float* __restrict__ gumbel,
                 float* __restrict__ ws) {
  const int blk  = blockIdx.x;
  const int tid  = threadIdx.x;
  const int wave = tid >> 6, lane = tid & 63;
  const int b = blk >> 4, c = blk & 15;
  const size_t gbase = (size_t)blk << 10;

  const f4 lv = *(const f4*)(logits + gbase + (tid << 2));
  const f4 gv = *(const f4*)(gumbel + gbase + (tid << 2));
  float x[4];
#pragma unroll
  for (int e = 0; e < 4; ++e) x[e] = lv[e] + gv[e];
  const int myn = (c << 10) + (tid << 2);   // row-local index of x[0]

  __shared__ float sv[64];
  __shared__ int   si[64];
  __shared__ float spart[5];
  __shared__ float smc;

  // wave-local sequential top-16 over 256 elements (no barriers)
#pragma unroll 1
  for (int k = 0; k < K; ++k) {
    float vmax = -INFINITY; int imax = 0x7fffffff;
#pragma unroll
    for (int e = 0; e < 4; ++e)
      if (x[e] > vmax) { vmax = x[e]; imax = myn + e; }   // ascending e: first wins ties
    wave_argmax(vmax, imax);
    if (lane == 0) { sv[wave * K + k] = vmax; si[wave * K + k] = imax; }
#pragma unroll
    for (int e = 0; e < 4; ++e)
      if (myn + e == imax) x[e] = -INFINITY;
  }
  __syncthreads();

  // wave 0: merge 64 wave-candidates -> chunk top-16, write to ws
  if (wave == 0) {
    float cv = sv[lane]; int ci = si[lane];
    float mc = 0.f;
    float* wV = ws + ((size_t)b * NCHUNK + c) * K;
    int*   wI = (int*)(ws + WSI_OFF) + ((size_t)b * NCHUNK + c) * K;
#pragma unroll 1
    for (int k = 0; k < K; ++k) {
      float vmax = cv; int imax = ci;
      wave_argmax(vmax, imax);
      if (k == 0) { mc = vmax; if (lane == 0) smc = vmax; }
      if (lane == 0) { wV[k] = vmax; wI[k] = imax; }
      if (ci == imax) cv = -INFINITY;
    }
    // leftover: the 48 unselected wave-candidates go back into the chunk sum
    float ls = wave_sum(__expf((cv - mc) * 1.5f));
    if (lane == 0) spart[4] = ls;
  }
  __syncthreads();

  const float mc = smc;
  float p = 0.f;
#pragma unroll
  for (int e = 0; e < 4; ++e) p += __expf((x[e] - mc) * 1.5f);  // masked -> exp(-inf)=0
  p = wave_sum(p);
  if (lane == 0) spart[wave] = p;
  __syncthreads();

  if (tid == 0) {
    const float S = spart[0] + spart[1] + spart[2] + spart[3] + spart[4];
    (ws + WSS_OFF)[b * NCHUNK + c] = S;
    (ws + WSM_OFF)[b * NCHUNK + c] = mc;
  }
}

// ---------------- Kernel M: one wave per row merges 256 candidates -> constants ----------------
// 64 blocks x 64 threads. FULLY UNROLLED merge: ev[]/ei[] stay in registers.
__global__ __launch_bounds__(64)
void gtk_merge(float* __restrict__ ws) {
  const int b    = blockIdx.x;
  const int lane = threadIdx.x;

  const float* wV = ws + (size_t)b * (NCHUNK * K);
  const int*   wI = (const int*)(ws + WSI_OFF) + (size_t)b * (NCHUNK * K);

  float cv[4]; int ci[4];
#pragma unroll
  for (int r = 0; r < 4; ++r) { cv[r] = wV[lane + 64 * r]; ci[r] = wI[lane + 64 * r]; }

  float ev[K]; int ei[K];
#pragma unroll
  for (int k = 0; k < K; ++k) {       // full unroll: ev[k]/ei[k] static
    float vmax = -INFINITY; int imax = 0x7fffffff;
#pragma unroll
    for (int r = 0; r < 4; ++r)
      if (cv[r] > vmax || (cv[r] == vmax && ci[r] < imax)) { vmax = cv[r]; imax = ci[r]; }
    wave_argmax(vmax, imax);
    ev[k] = vmax; ei[k] = imax;
#pragma unroll
    for (int r = 0; r < 4; ++r)
      if (ci[r] == imax) cv[r] = -INFINITY;
  }

  const float m0 = ev[0];
  // A' = unselected candidates (add-back) + rescaled chunk sums
  float acc = 0.f;
#pragma unroll
  for (int r = 0; r < 4; ++r) acc += __expf((cv[r] - m0) * 1.5f);
  if (lane < NCHUNK) {
    const float S  = (ws + WSS_OFF)[b * NCHUNK + lane];
    const float mc = (ws + WSM_OFF)[b * NCHUNK + lane];
    acc += S * __expf((mc - m0) * 1.5f);
  }
  const float A = wave_sum(acc);

  if (lane == 0) {
    float* wrow = ws + WSC_OFF + (size_t)b * 48;
    float T = 0.f;
    float c[K];
#pragma unroll
    for (int j = K - 1; j >= 0; --j) { T += __expf((ev[j] - m0) * 1.5f); c[j] = 1.0f / (A + T); }
#pragma unroll
    for (int j = 0; j < K; ++j) wrow[j] = c[j];
    int* wi = (int*)(wrow + K);
#pragma unroll
    for (int j = 0; j < K; ++j) wi[j] = ei[j];
    wrow[32] = m0;
  }
}

// ---------------- Kernel B: write st (one-hot) and softs (E * c_k) ----------------
// 1024 blocks x 256 threads; each thread owns 4 consecutive n; nontemporal float4 stores.
__global__ __launch_bounds__(256)
void gtk_write(const float* __restrict__ logits, const float* __restrict__ gumbel,
               const float* __restrict__ ws, float* __restrict__ st,
               float* __restrict__ softs) {
  const int blk = blockIdx.x;
  const int tid = threadIdx.x;
  const int b   = blk >> 4;
  const size_t o = ((size_t)blk << 10) + (tid << 2);   // global element index
  const int n0  = ((blk & 15) << 10) + (tid << 2);     // row-local index

  __shared__ float sc[K];
  __shared__ int   sidx[K];
  __shared__ float sm0;
  const float* wrow = ws + WSC_OFF + (size_t)b * 48;
  if (tid < K) {
    sc[tid]   = wrow[tid];
    sidx[tid] = ((const int*)(wrow + K))[tid];
  }
  if (tid == 0) sm0 = wrow[32];

  const f4 lv = *(const f4*)(logits + o);
  const f4 gv = *(const f4*)(gumbel + o);
  __syncthreads();

  const float m0 = sm0;
  float E[4];
#pragma unroll
  for (int e = 0; e < 4; ++e) E[e] = __expf((lv[e] + gv[e] - m0) * 1.5f);

  int js[4] = {K, K, K, K};
#pragma unroll
  for (int j = 0; j < K; ++j) {
    const int idx = sidx[j];
#pragma unroll
    for (int e = 0; e < 4; ++e)
      if (idx == n0 + e) js[e] = j;
  }

  const size_t plane = (size_t)B * N;
#pragma unroll
  for (int k = 0; k < K; ++k) {
    const float ck = sc[k];
    f4 s, h;
#pragma unroll
    for (int e = 0; e < 4; ++e) {
      s[e] = (js[e] < k) ? 0.f : E[e] * ck;
      h[e] = (js[e] == k) ? 1.f : 0.f;
    }
    __builtin_nontemporal_store(s, (f4*)(softs + k * plane + o));
    __builtin_nontemporal_store(h, (f4*)(st    + k * plane + o));
  }
}

extern "C" void kernel_launch(void* const* d_in, const int* in_sizes, int n_in,
                              void* d_out, int out_size, void* d_ws, size_t ws_size,
                              hipStream_t stream) {
  const float* logits = (const float*)d_in[0];
  const float* gumbel = (const float*)d_in[1];
  float* st    = (float*)d_out;                      // [K,B,N]
  float* softs = st + (size_t)K * B * N;             // [K,B,N]
  float* ws    = (float*)d_ws;

  gtk_partial<<<B * NCHUNK, 256, 0, stream>>>(logits, gumbel, ws);
  gtk_merge<<<B, 64, 0, stream>>>(ws);
  gtk_write<<<B * NCHUNK, 256, 0, stream>>>(logits, gumbel, ws, st, softs);
}